// Round 7
// baseline (446.046 us; speedup 1.0000x reference)
//
#include <hip/hip_runtime.h>
#include <math.h>

#define N 4096
#define DD 256
#define CAP 640      // per-column candidate capacity (~331 expected w/ 64-row slab threshold)
#define RCAP 256     // per-row support capacity
#define LEAKY 0.2f

// ---------------------------------------------------------------------------
// Column candidate compaction via LDS transpose. Block = 256 thr, tile =
// 64 rows x 256 cols. Row-major coalesced float4 loads -> LDS (pad 257,
// conflict-free write: each wave writes one full row; conflict-free read:
// consecutive lanes read consecutive addresses). Per-column slab max over
// 64 rows gives threshold m64-1; tau*_j >= M_j-1 >= m_slab-1, so the
// compacted set is a conservative superset (Michelot on a superset is exact).
// Expected ~5 candidates/col/tile -> rare scattered atomics.
// ---------------------------------------------------------------------------
__global__ __launch_bounds__(256) void k_colcand3(const float* __restrict__ cost,
      int* __restrict__ cnt, float* __restrict__ candv, int* __restrict__ candi){
  __shared__ float s[64][257];
  const int t = threadIdx.x, lane = t & 63, w = t >> 6;
  const int c0 = blockIdx.x * 256;
  const int r0 = blockIdx.y * 64;

  #pragma unroll
  for (int rep = 0; rep < 16; ++rep){
    const int row = rep * 4 + w;
    const float4 v = *(const float4*)(cost + (size_t)(r0 + row) * N + c0 + 4 * lane);
    float* dst = &s[row][4 * lane];
    dst[0] = -v.x; dst[1] = -v.y; dst[2] = -v.z; dst[3] = -v.w;
  }
  __syncthreads();

  const int j = c0 + t;
  float m = s[0][t];
  #pragma unroll
  for (int r = 1; r < 64; ++r) m = fmaxf(m, s[r][t]);
  const float th = m - 1.0f;

  #pragma unroll 4
  for (int r = 0; r < 64; ++r){
    float x = s[r][t];
    if (x > th){
      int q = atomicAdd(&cnt[j], 1);
      if (q < CAP){
        candv[(size_t)j * CAP + q] = x;
        candi[(size_t)j * CAP + q] = r0 + r;
      }
    }
  }
}

// ---------------------------------------------------------------------------
// Column tau (Michelot on candidates, one wave per column) + alpha[j,:].
// ---------------------------------------------------------------------------
__global__ __launch_bounds__(256) void k_coltau(const int* __restrict__ cnt,
      const float* __restrict__ candv, const int* __restrict__ candi,
      const float* __restrict__ rowvecs, float* __restrict__ tau_out,
      float* __restrict__ alpha){
  const int t = threadIdx.x, w = t >> 6, lane = t & 63;
  const int j = blockIdx.x * 4 + w;
  const int c = min(cnt[j], CAP);
  const float* cv = candv + (size_t)j * CAP;
  const int*   ci = candi + (size_t)j * CAP;

  float v[10]; int id[10];
  #pragma unroll
  for (int s = 0; s < 10; ++s){
    int l = s * 64 + lane;
    v[s]  = (l < c) ? cv[l] : -3.4e38f;
    id[s] = (l < c) ? ci[l] : 0;
  }

  float tau = -3.0e38f;
  for (int it = 0; it < 40; ++it){
    float sum = 0.0f, cf = 0.0f;
    #pragma unroll
    for (int s = 0; s < 10; ++s) if (v[s] > tau){ sum += v[s]; cf += 1.0f; }
    for (int off = 32; off; off >>= 1){ sum += __shfl_xor(sum, off); cf += __shfl_xor(cf, off); }
    float nt = (sum - 1.0f) / cf;
    if (nt == tau) break;
    tau = nt;
  }
  if (lane == 0) tau_out[j] = tau;

  // compact support (p = v - tau > 0) into per-wave LDS
  __shared__ float sup_v[4][CAP];
  __shared__ int   sup_i[4][CAP];
  int base = 0;
  #pragma unroll
  for (int s = 0; s < 10; ++s){
    bool pred = (v[s] > tau);
    unsigned long long mk = __ballot(pred);
    if (pred){
      int pos = base + __popcll(mk & ((1ULL << lane) - 1ULL));
      sup_v[w][pos] = v[s] - tau;
      sup_i[w][pos] = id[s];
    }
    base += __popcll(mk);
  }
  const int ns = base;
  __builtin_amdgcn_wave_barrier();
  __asm__ volatile("s_waitcnt lgkmcnt(0)");

  float a0 = 0, a1 = 0, a2 = 0, a3 = 0;
  #pragma unroll 4
  for (int l = 0; l < ns; ++l){
    float pp = sup_v[w][l];
    const float* ar = rowvecs + (size_t)sup_i[w][l] * DD;
    a0 += pp * ar[lane];        a1 += pp * ar[64 + lane];
    a2 += pp * ar[128 + lane];  a3 += pp * ar[192 + lane];
  }
  float* al = alpha + (size_t)j * DD;
  al[lane] = a0; al[64 + lane] = a1; al[128 + lane] = a2; al[192 + lane] = a3;
}

// ---------------------------------------------------------------------------
// Row sparsemax, FUSED: reads cost row once; writes row_alignment AND
// column_alignment; accumulates beta[i,:].
// ---------------------------------------------------------------------------
__global__ __launch_bounds__(256) void k_row(const float* __restrict__ cost,
      const float* __restrict__ colvecs, const float* __restrict__ tau_col,
      float* __restrict__ out_row, float* __restrict__ out_col,
      float* __restrict__ beta){
  const int i = blockIdx.x, t = threadIdx.x;
  const int w = t >> 6, lane = t & 63;
  __shared__ float s_red[4];
  __shared__ float s_M, s_tau, s_b;
  __shared__ int   s_cnt, s_cnt2;
  __shared__ float s_cv[RCAP];
  __shared__ int   s_cj[RCAP];

  const float4* row4 = (const float4*)(cost + (size_t)i * N);
  const float4* tau4 = (const float4*)tau_col;
  float4 x4[4], tt4[4];
  #pragma unroll
  for (int q = 0; q < 4; ++q){
    float4 v = row4[t + q * 256];
    x4[q] = make_float4(-v.x, -v.y, -v.z, -v.w);
    tt4[q] = tau4[t + q * 256];
  }
  float m = -3.4e38f;
  #pragma unroll
  for (int q = 0; q < 4; ++q)
    m = fmaxf(m, fmaxf(fmaxf(x4[q].x, x4[q].y), fmaxf(x4[q].z, x4[q].w)));
  for (int off = 32; off; off >>= 1) m = fmaxf(m, __shfl_xor(m, off));
  if (lane == 0) s_red[w] = m;
  if (t == 0){ s_cnt = 0; s_cnt2 = 0; }
  __syncthreads();
  if (t == 0) s_M = fmaxf(fmaxf(s_red[0], s_red[1]), fmaxf(s_red[2], s_red[3]));
  __syncthreads();
  const float M = s_M, th = M - 1.0f;

  #pragma unroll
  for (int q = 0; q < 4; ++q){
    const float* e = &x4[q].x;
    #pragma unroll
    for (int c = 0; c < 4; ++c){
      float v = e[c];
      if (v > th){ int p = atomicAdd(&s_cnt, 1); if (p < RCAP) s_cv[p] = v; }
    }
  }
  __syncthreads();
  int c = s_cnt;
  if (c <= RCAP){
    if (w == 0){
      float v[4];
      #pragma unroll
      for (int s = 0; s < 4; ++s){ int l = s * 64 + lane; v[s] = (l < c) ? s_cv[l] : -3.4e38f; }
      float tau = -3.0e38f;
      for (int it = 0; it < 40; ++it){
        float sum = 0.0f, cf = 0.0f;
        #pragma unroll
        for (int s = 0; s < 4; ++s) if (v[s] > tau){ sum += v[s]; cf += 1.0f; }
        for (int off = 32; off; off >>= 1){ sum += __shfl_xor(sum, off); cf += __shfl_xor(cf, off); }
        float nt = (sum - 1.0f) / cf;
        if (nt == tau) break;
        tau = nt;
      }
      if (lane == 0) s_tau = tau;
    }
    __syncthreads();
  } else {
    // fallback: block bisection on [M-1, M] (not taken for this input)
    float lo = th, hi = M;
    for (int it = 0; it < 40; ++it){
      float mid = 0.5f * (lo + hi);
      float part = 0.0f;
      #pragma unroll
      for (int q = 0; q < 4; ++q){
        const float* e = &x4[q].x;
        #pragma unroll
        for (int cc = 0; cc < 4; ++cc) part += fmaxf(e[cc] - mid, 0.0f);
      }
      for (int off = 32; off; off >>= 1) part += __shfl_xor(part, off);
      if (lane == 0) s_red[w] = part;
      __syncthreads();
      if (t == 0) s_b = s_red[0] + s_red[1] + s_red[2] + s_red[3];
      __syncthreads();
      if (s_b >= 1.0f) lo = mid; else hi = mid;
      __syncthreads();
    }
    if (t == 0) s_tau = lo;
    __syncthreads();
  }
  const float tau = s_tau;

  float4* orow4 = (float4*)(out_row + (size_t)i * N);
  float4* ocol4 = (float4*)(out_col + (size_t)i * N);
  #pragma unroll
  for (int q = 0; q < 4; ++q){
    float4 p;
    p.x = fmaxf(x4[q].x - tau, 0.0f);
    p.y = fmaxf(x4[q].y - tau, 0.0f);
    p.z = fmaxf(x4[q].z - tau, 0.0f);
    p.w = fmaxf(x4[q].w - tau, 0.0f);
    orow4[t + q * 256] = p;

    float4 pc;
    pc.x = fmaxf(x4[q].x - tt4[q].x, 0.0f);
    pc.y = fmaxf(x4[q].y - tt4[q].y, 0.0f);
    pc.z = fmaxf(x4[q].z - tt4[q].z, 0.0f);
    pc.w = fmaxf(x4[q].w - tt4[q].w, 0.0f);
    ocol4[t + q * 256] = pc;

    int jb = 4 * (t + q * 256);
    const float* e = &p.x;
    #pragma unroll
    for (int cc = 0; cc < 4; ++cc){
      if (e[cc] > 0.0f){
        int l = atomicAdd(&s_cnt2, 1);
        if (l < RCAP){ s_cv[l] = e[cc]; s_cj[l] = jb + cc; }
      }
    }
  }
  __syncthreads();
  int ns = min(s_cnt2, RCAP);
  float acc = 0.0f;
  #pragma unroll 4
  for (int l = 0; l < ns; ++l)
    acc += s_cv[l] * colvecs[(size_t)s_cj[l] * DD + t];
  beta[(size_t)i * DD + t] = acc;
}

// ---------------------------------------------------------------------------
// G(x) = leaky_relu(x @ W + b); accumulate column sums for the means
// ---------------------------------------------------------------------------
__global__ __launch_bounds__(256) void k_G(const float* __restrict__ beta,
      const float* __restrict__ alpha, const float* __restrict__ W,
      const float* __restrict__ bG, float* __restrict__ vsum){
  int t = threadIdx.x, side = blockIdx.y, r0 = blockIdx.x * 16;
  const float* src = side ? alpha : beta;
  __shared__ float sB[16 * 256];
  #pragma unroll
  for (int k = 0; k < 16; ++k) sB[k * 256 + t] = src[(size_t)(r0 + k) * 256 + t];
  __syncthreads();
  float acc[16];
  float bg = bG[t];
  #pragma unroll
  for (int r = 0; r < 16; ++r) acc[r] = bg;
  const float4* sB4 = (const float4*)sB;
  for (int d4 = 0; d4 < 64; ++d4){
    int d = d4 * 4;
    float w0 = W[(size_t)d * 256 + t];
    float w1 = W[(size_t)(d + 1) * 256 + t];
    float w2 = W[(size_t)(d + 2) * 256 + t];
    float w3 = W[(size_t)(d + 3) * 256 + t];
    #pragma unroll
    for (int r = 0; r < 16; ++r){
      float4 s = sB4[r * 64 + d4];
      acc[r] += s.x * w0 + s.y * w1 + s.z * w2 + s.w * w3;
    }
  }
  float s = 0.0f;
  #pragma unroll
  for (int r = 0; r < 16; ++r){ float u = acc[r]; s += (u > 0.0f) ? u : LEAKY * u; }
  atomicAdd(&vsum[side * 256 + t], s);
}

// cosine cost scalar
__global__ __launch_bounds__(256) void k_final(const float* __restrict__ vsum,
                                               float* __restrict__ y){
  int t = threadIdx.x, w = t >> 6, lane = t & 63;
  __shared__ float rd[3][4];
  float v1 = vsum[t]       * (1.0f / 4096.0f);
  float v2 = vsum[256 + t] * (1.0f / 4096.0f);
  float d = v1 * v2, a = v1 * v1, b = v2 * v2;
  for (int off = 32; off; off >>= 1){
    d += __shfl_xor(d, off); a += __shfl_xor(a, off); b += __shfl_xor(b, off);
  }
  if (lane == 0){ rd[0][w] = d; rd[1][w] = a; rd[2][w] = b; }
  __syncthreads();
  if (t == 0){
    float dd = rd[0][0] + rd[0][1] + rd[0][2] + rd[0][3];
    float aa = rd[1][0] + rd[1][1] + rd[1][2] + rd[1][3];
    float bb = rd[2][0] + rd[2][1] + rd[2][2] + rd[2][3];
    y[0] = 1.0f - dd / (sqrtf(aa) * sqrtf(bb) + 1e-8f);
  }
}

// write-only broadcast of y into out0
__global__ __launch_bounds__(256) void k_fill(const float* __restrict__ ypt,
                                              float4* __restrict__ out0){
  int idx = blockIdx.x * 256 + threadIdx.x;
  float y = ypt[0];
  out0[idx] = make_float4(y, y, y, y);
}

extern "C" void kernel_launch(void* const* d_in, const int* in_sizes, int n_in,
                              void* d_out, int out_size, void* d_ws, size_t ws_size,
                              hipStream_t stream){
  const float* rowv = (const float*)d_in[0];   // [4096,256]
  const float* colv = (const float*)d_in[1];   // [4096,256]
  const float* cost = (const float*)d_in[2];   // [4096,4096]
  const float* W    = (const float*)d_in[3];   // [256,256]
  const float* bG   = (const float*)d_in[4];   // [256]

  float* out0    = (float*)d_out;
  float* out_row = out0 + (size_t)N * N;
  float* out_col = out0 + 2 * (size_t)N * N;

  // ws layout (float units): cnt[4096] vsum[512] tau[4096] beta[1M] alpha[1M]
  //                          candv[4096*640] candi[4096*640] ypt[1]
  int*   cnt   = (int*)d_ws;
  float* vsum  = (float*)d_ws + 4096;
  float* tau   = (float*)d_ws + 4608;
  float* beta  = (float*)d_ws + 8704;
  float* alpha = (float*)d_ws + 8704 + 1048576;
  float* candv = (float*)d_ws + 8704 + 2 * 1048576;
  int*   candi = (int*)d_ws   + 8704 + 2 * 1048576 + 2621440;
  float* ypt   = (float*)d_ws + 8704 + 2 * 1048576 + 2 * 2621440;

  hipMemsetAsync(d_ws, 0, (size_t)4608 * 4, stream);

  hipLaunchKernelGGL(k_colcand3, dim3(16, 64), dim3(256), 0, stream, cost, cnt, candv, candi);
  hipLaunchKernelGGL(k_coltau,   dim3(1024),   dim3(256), 0, stream, cnt, candv, candi, rowv, tau, alpha);
  hipLaunchKernelGGL(k_row,      dim3(4096),   dim3(256), 0, stream, cost, colv, tau, out_row, out_col, beta);
  hipLaunchKernelGGL(k_G,        dim3(256,2),  dim3(256), 0, stream, beta, alpha, W, bG, vsum);
  hipLaunchKernelGGL(k_final,    dim3(1),      dim3(256), 0, stream, vsum, ypt);
  hipLaunchKernelGGL(k_fill,     dim3(16384),  dim3(256), 0, stream, ypt, (float4*)out0);
}

// Round 8
// 358.109 us; speedup vs baseline: 1.2456x; 1.2456x over previous
//
#include <hip/hip_runtime.h>
#include <math.h>

#define N 4096
#define DD 256
#define CAP 512      // per-column candidate capacity (~26 expected w/ exact threshold)
#define RCAP 256     // per-row support capacity
#define LEAKY 0.2f

// ---- monotone float<->uint map for atomicMax on floats ----
__device__ __forceinline__ unsigned fmap(float f){
  unsigned u = __float_as_uint(f);
  return (u & 0x80000000u) ? ~u : (u | 0x80000000u);
}
__device__ __forceinline__ float funmap(unsigned u){
  unsigned b = (u & 0x80000000u) ? (u & 0x7fffffffu) : ~u;
  return __uint_as_float(b);
}

// ---------------------------------------------------------------------------
// Pass A: exact per-column max. No transpose needed: thread t owns 4 FIXED
// columns (c0+4*lane..+3) and strides rows by 4 (w + 4*it). Every wave load
// is a contiguous 1 KB segment. One fire-and-forget atomicMax per column per
// block (no dependent use -> fully latency-hidden).
// ---------------------------------------------------------------------------
__global__ __launch_bounds__(256) void k_colmax(const float* __restrict__ cost,
                                                unsigned* __restrict__ colmax){
  const int t = threadIdx.x, lane = t & 63, w = t >> 6;
  const int c0 = blockIdx.x * 256;
  const int r0 = blockIdx.y * 128;
  const float* p = cost + (size_t)(r0 + w) * N + c0 + 4 * lane;

  float m0 = -3.4e38f, m1 = m0, m2 = m0, m3 = m0;
  #pragma unroll
  for (int it = 0; it < 32; ++it){
    float4 v = *(const float4*)(p + (size_t)(4 * it) * N);
    m0 = fmaxf(m0, -v.x); m1 = fmaxf(m1, -v.y);
    m2 = fmaxf(m2, -v.z); m3 = fmaxf(m3, -v.w);
  }
  __shared__ float s[4][256];
  float* d = &s[w][4 * lane];
  d[0] = m0; d[1] = m1; d[2] = m2; d[3] = m3;
  __syncthreads();
  float m = fmaxf(fmaxf(s[0][t], s[1][t]), fmaxf(s[2][t], s[3][t]));
  atomicMax(&colmax[c0 + t], fmap(m));
}

// ---------------------------------------------------------------------------
// Pass B: candidate compaction with the EXACT threshold M_j - 1 (so the set
// is exactly {x > M_j-1} >= support; Michelot on it is exact). ~26 cands/col
// total -> ~0.4 per thread. Candidate = one 8 B float2{val, row} store.
// ---------------------------------------------------------------------------
__global__ __launch_bounds__(256) void k_colcand(const float* __restrict__ cost,
      const unsigned* __restrict__ colmax, int* __restrict__ cnt,
      float2* __restrict__ cand){
  const int t = threadIdx.x, lane = t & 63, w = t >> 6;
  const int c0 = blockIdx.x * 256;
  const int r0 = blockIdx.y * 128;
  const int jb = c0 + 4 * lane;

  const uint4 cm = *(const uint4*)(colmax + jb);
  const float th0 = funmap(cm.x) - 1.0f;
  const float th1 = funmap(cm.y) - 1.0f;
  const float th2 = funmap(cm.z) - 1.0f;
  const float th3 = funmap(cm.w) - 1.0f;

  const float* p = cost + (size_t)(r0 + w) * N + jb;
  #pragma unroll 8
  for (int it = 0; it < 32; ++it){
    float4 v = *(const float4*)(p + (size_t)(4 * it) * N);
    const int r = r0 + w + 4 * it;
    float x;
    x = -v.x; if (x > th0){ int q = atomicAdd(&cnt[jb+0], 1); if (q < CAP) cand[(size_t)(jb+0)*CAP + q] = make_float2(x, __int_as_float(r)); }
    x = -v.y; if (x > th1){ int q = atomicAdd(&cnt[jb+1], 1); if (q < CAP) cand[(size_t)(jb+1)*CAP + q] = make_float2(x, __int_as_float(r)); }
    x = -v.z; if (x > th2){ int q = atomicAdd(&cnt[jb+2], 1); if (q < CAP) cand[(size_t)(jb+2)*CAP + q] = make_float2(x, __int_as_float(r)); }
    x = -v.w; if (x > th3){ int q = atomicAdd(&cnt[jb+3], 1); if (q < CAP) cand[(size_t)(jb+3)*CAP + q] = make_float2(x, __int_as_float(r)); }
  }
}

// ---------------------------------------------------------------------------
// Column tau (Michelot on candidates, one wave per column) + alpha[j,:].
// ---------------------------------------------------------------------------
__global__ __launch_bounds__(256) void k_coltau(const int* __restrict__ cnt,
      const float2* __restrict__ cand, const float* __restrict__ rowvecs,
      float* __restrict__ tau_out, float* __restrict__ alpha){
  const int t = threadIdx.x, w = t >> 6, lane = t & 63;
  const int j = blockIdx.x * 4 + w;
  const int c = min(cnt[j], CAP);
  const float2* cd = cand + (size_t)j * CAP;

  float v[8]; int id[8];
  #pragma unroll
  for (int s = 0; s < 8; ++s){
    int l = s * 64 + lane;
    if (l < c){ float2 e = cd[l]; v[s] = e.x; id[s] = __float_as_int(e.y); }
    else      { v[s] = -3.4e38f;  id[s] = 0; }
  }

  float tau = -3.0e38f;
  for (int it = 0; it < 40; ++it){
    float sum = 0.0f, cf = 0.0f;
    #pragma unroll
    for (int s = 0; s < 8; ++s) if (v[s] > tau){ sum += v[s]; cf += 1.0f; }
    for (int off = 32; off; off >>= 1){ sum += __shfl_xor(sum, off); cf += __shfl_xor(cf, off); }
    float nt = (sum - 1.0f) / cf;
    if (nt == tau) break;
    tau = nt;
  }
  if (lane == 0) tau_out[j] = tau;

  // compact support (p = v - tau > 0) into per-wave LDS
  __shared__ float sup_v[4][CAP];
  __shared__ int   sup_i[4][CAP];
  int base = 0;
  #pragma unroll
  for (int s = 0; s < 8; ++s){
    bool pred = (v[s] > tau);
    unsigned long long mk = __ballot(pred);
    if (pred){
      int pos = base + __popcll(mk & ((1ULL << lane) - 1ULL));
      sup_v[w][pos] = v[s] - tau;
      sup_i[w][pos] = id[s];
    }
    base += __popcll(mk);
  }
  const int ns = base;
  __builtin_amdgcn_wave_barrier();
  __asm__ volatile("s_waitcnt lgkmcnt(0)");

  float a0 = 0, a1 = 0, a2 = 0, a3 = 0;
  #pragma unroll 4
  for (int l = 0; l < ns; ++l){
    float pp = sup_v[w][l];
    const float* ar = rowvecs + (size_t)sup_i[w][l] * DD;
    a0 += pp * ar[lane];        a1 += pp * ar[64 + lane];
    a2 += pp * ar[128 + lane];  a3 += pp * ar[192 + lane];
  }
  float* al = alpha + (size_t)j * DD;
  al[lane] = a0; al[64 + lane] = a1; al[128 + lane] = a2; al[192 + lane] = a3;
}

// ---------------------------------------------------------------------------
// Row sparsemax, FUSED: reads cost row once; writes row_alignment AND
// column_alignment; accumulates beta[i,:].
// ---------------------------------------------------------------------------
__global__ __launch_bounds__(256) void k_row(const float* __restrict__ cost,
      const float* __restrict__ colvecs, const float* __restrict__ tau_col,
      float* __restrict__ out_row, float* __restrict__ out_col,
      float* __restrict__ beta){
  const int i = blockIdx.x, t = threadIdx.x;
  const int w = t >> 6, lane = t & 63;
  __shared__ float s_red[4];
  __shared__ float s_M, s_tau, s_b;
  __shared__ int   s_cnt, s_cnt2;
  __shared__ float s_cv[RCAP];
  __shared__ int   s_cj[RCAP];

  const float4* row4 = (const float4*)(cost + (size_t)i * N);
  const float4* tau4 = (const float4*)tau_col;
  float4 x4[4], tt4[4];
  #pragma unroll
  for (int q = 0; q < 4; ++q){
    float4 v = row4[t + q * 256];
    x4[q] = make_float4(-v.x, -v.y, -v.z, -v.w);
    tt4[q] = tau4[t + q * 256];
  }
  float m = -3.4e38f;
  #pragma unroll
  for (int q = 0; q < 4; ++q)
    m = fmaxf(m, fmaxf(fmaxf(x4[q].x, x4[q].y), fmaxf(x4[q].z, x4[q].w)));
  for (int off = 32; off; off >>= 1) m = fmaxf(m, __shfl_xor(m, off));
  if (lane == 0) s_red[w] = m;
  if (t == 0){ s_cnt = 0; s_cnt2 = 0; }
  __syncthreads();
  if (t == 0) s_M = fmaxf(fmaxf(s_red[0], s_red[1]), fmaxf(s_red[2], s_red[3]));
  __syncthreads();
  const float M = s_M, th = M - 1.0f;

  #pragma unroll
  for (int q = 0; q < 4; ++q){
    const float* e = &x4[q].x;
    #pragma unroll
    for (int c = 0; c < 4; ++c){
      float v = e[c];
      if (v > th){ int p = atomicAdd(&s_cnt, 1); if (p < RCAP) s_cv[p] = v; }
    }
  }
  __syncthreads();
  int c = s_cnt;
  if (c <= RCAP){
    if (w == 0){
      float v[4];
      #pragma unroll
      for (int s = 0; s < 4; ++s){ int l = s * 64 + lane; v[s] = (l < c) ? s_cv[l] : -3.4e38f; }
      float tau = -3.0e38f;
      for (int it = 0; it < 40; ++it){
        float sum = 0.0f, cf = 0.0f;
        #pragma unroll
        for (int s = 0; s < 4; ++s) if (v[s] > tau){ sum += v[s]; cf += 1.0f; }
        for (int off = 32; off; off >>= 1){ sum += __shfl_xor(sum, off); cf += __shfl_xor(cf, off); }
        float nt = (sum - 1.0f) / cf;
        if (nt == tau) break;
        tau = nt;
      }
      if (lane == 0) s_tau = tau;
    }
    __syncthreads();
  } else {
    // fallback: block bisection on [M-1, M] (not taken for this input)
    float lo = th, hi = M;
    for (int it = 0; it < 40; ++it){
      float mid = 0.5f * (lo + hi);
      float part = 0.0f;
      #pragma unroll
      for (int q = 0; q < 4; ++q){
        const float* e = &x4[q].x;
        #pragma unroll
        for (int cc = 0; cc < 4; ++cc) part += fmaxf(e[cc] - mid, 0.0f);
      }
      for (int off = 32; off; off >>= 1) part += __shfl_xor(part, off);
      if (lane == 0) s_red[w] = part;
      __syncthreads();
      if (t == 0) s_b = s_red[0] + s_red[1] + s_red[2] + s_red[3];
      __syncthreads();
      if (s_b >= 1.0f) lo = mid; else hi = mid;
      __syncthreads();
    }
    if (t == 0) s_tau = lo;
    __syncthreads();
  }
  const float tau = s_tau;

  float4* orow4 = (float4*)(out_row + (size_t)i * N);
  float4* ocol4 = (float4*)(out_col + (size_t)i * N);
  #pragma unroll
  for (int q = 0; q < 4; ++q){
    float4 p;
    p.x = fmaxf(x4[q].x - tau, 0.0f);
    p.y = fmaxf(x4[q].y - tau, 0.0f);
    p.z = fmaxf(x4[q].z - tau, 0.0f);
    p.w = fmaxf(x4[q].w - tau, 0.0f);
    orow4[t + q * 256] = p;

    float4 pc;
    pc.x = fmaxf(x4[q].x - tt4[q].x, 0.0f);
    pc.y = fmaxf(x4[q].y - tt4[q].y, 0.0f);
    pc.z = fmaxf(x4[q].z - tt4[q].z, 0.0f);
    pc.w = fmaxf(x4[q].w - tt4[q].w, 0.0f);
    ocol4[t + q * 256] = pc;

    int jb = 4 * (t + q * 256);
    const float* e = &p.x;
    #pragma unroll
    for (int cc = 0; cc < 4; ++cc){
      if (e[cc] > 0.0f){
        int l = atomicAdd(&s_cnt2, 1);
        if (l < RCAP){ s_cv[l] = e[cc]; s_cj[l] = jb + cc; }
      }
    }
  }
  __syncthreads();
  int ns = min(s_cnt2, RCAP);
  float acc = 0.0f;
  #pragma unroll 4
  for (int l = 0; l < ns; ++l)
    acc += s_cv[l] * colvecs[(size_t)s_cj[l] * DD + t];
  beta[(size_t)i * DD + t] = acc;
}

// ---------------------------------------------------------------------------
// G(x) = leaky_relu(x @ W + b); accumulate column sums for the means
// ---------------------------------------------------------------------------
__global__ __launch_bounds__(256) void k_G(const float* __restrict__ beta,
      const float* __restrict__ alpha, const float* __restrict__ W,
      const float* __restrict__ bG, float* __restrict__ vsum){
  int t = threadIdx.x, side = blockIdx.y, r0 = blockIdx.x * 16;
  const float* src = side ? alpha : beta;
  __shared__ float sB[16 * 256];
  #pragma unroll
  for (int k = 0; k < 16; ++k) sB[k * 256 + t] = src[(size_t)(r0 + k) * 256 + t];
  __syncthreads();
  float acc[16];
  float bg = bG[t];
  #pragma unroll
  for (int r = 0; r < 16; ++r) acc[r] = bg;
  const float4* sB4 = (const float4*)sB;
  for (int d4 = 0; d4 < 64; ++d4){
    int d = d4 * 4;
    float w0 = W[(size_t)d * 256 + t];
    float w1 = W[(size_t)(d + 1) * 256 + t];
    float w2 = W[(size_t)(d + 2) * 256 + t];
    float w3 = W[(size_t)(d + 3) * 256 + t];
    #pragma unroll
    for (int r = 0; r < 16; ++r){
      float4 s = sB4[r * 64 + d4];
      acc[r] += s.x * w0 + s.y * w1 + s.z * w2 + s.w * w3;
    }
  }
  float s = 0.0f;
  #pragma unroll
  for (int r = 0; r < 16; ++r){ float u = acc[r]; s += (u > 0.0f) ? u : LEAKY * u; }
  atomicAdd(&vsum[side * 256 + t], s);
}

// cosine cost scalar
__global__ __launch_bounds__(256) void k_final(const float* __restrict__ vsum,
                                               float* __restrict__ y){
  int t = threadIdx.x, w = t >> 6, lane = t & 63;
  __shared__ float rd[3][4];
  float v1 = vsum[t]       * (1.0f / 4096.0f);
  float v2 = vsum[256 + t] * (1.0f / 4096.0f);
  float d = v1 * v2, a = v1 * v1, b = v2 * v2;
  for (int off = 32; off; off >>= 1){
    d += __shfl_xor(d, off); a += __shfl_xor(a, off); b += __shfl_xor(b, off);
  }
  if (lane == 0){ rd[0][w] = d; rd[1][w] = a; rd[2][w] = b; }
  __syncthreads();
  if (t == 0){
    float dd = rd[0][0] + rd[0][1] + rd[0][2] + rd[0][3];
    float aa = rd[1][0] + rd[1][1] + rd[1][2] + rd[1][3];
    float bb = rd[2][0] + rd[2][1] + rd[2][2] + rd[2][3];
    y[0] = 1.0f - dd / (sqrtf(aa) * sqrtf(bb) + 1e-8f);
  }
}

// write-only broadcast of y into out0
__global__ __launch_bounds__(256) void k_fill(const float* __restrict__ ypt,
                                              float4* __restrict__ out0){
  int idx = blockIdx.x * 256 + threadIdx.x;
  float y = ypt[0];
  out0[idx] = make_float4(y, y, y, y);
}

extern "C" void kernel_launch(void* const* d_in, const int* in_sizes, int n_in,
                              void* d_out, int out_size, void* d_ws, size_t ws_size,
                              hipStream_t stream){
  const float* rowv = (const float*)d_in[0];   // [4096,256]
  const float* colv = (const float*)d_in[1];   // [4096,256]
  const float* cost = (const float*)d_in[2];   // [4096,4096]
  const float* W    = (const float*)d_in[3];   // [256,256]
  const float* bG   = (const float*)d_in[4];   // [256]

  float* out0    = (float*)d_out;
  float* out_row = out0 + (size_t)N * N;
  float* out_col = out0 + 2 * (size_t)N * N;

  // ws layout (float units): cnt[4096] vsum[512] colmax[4096] tau[4096]
  //                          beta[1M] alpha[1M] cand(float2)[4096*512] ypt[1]
  int*      cnt    = (int*)d_ws;
  float*    vsum   = (float*)d_ws + 4096;
  unsigned* colmax = (unsigned*)d_ws + 4608;
  float*    tau    = (float*)d_ws + 8704;
  float*    beta   = (float*)d_ws + 12800;
  float*    alpha  = (float*)d_ws + 12800 + 1048576;
  float2*   cand   = (float2*)((float*)d_ws + 12800 + 2 * 1048576);
  float*    ypt    = (float*)d_ws + 12800 + 2 * 1048576 + 2 * (4096 * CAP);

  // zero cnt + vsum + colmax (contiguous prefix; 0 < fmap(any float))
  hipMemsetAsync(d_ws, 0, (size_t)8704 * 4, stream);

  hipLaunchKernelGGL(k_colmax,  dim3(16, 32), dim3(256), 0, stream, cost, colmax);
  hipLaunchKernelGGL(k_colcand, dim3(16, 32), dim3(256), 0, stream, cost, colmax, cnt, cand);
  hipLaunchKernelGGL(k_coltau,  dim3(1024),   dim3(256), 0, stream, cnt, cand, rowv, tau, alpha);
  hipLaunchKernelGGL(k_row,     dim3(4096),   dim3(256), 0, stream, cost, colv, tau, out_row, out_col, beta);
  hipLaunchKernelGGL(k_G,       dim3(256,2),  dim3(256), 0, stream, beta, alpha, W, bG, vsum);
  hipLaunchKernelGGL(k_final,   dim3(1),      dim3(256), 0, stream, vsum, ypt);
  hipLaunchKernelGGL(k_fill,    dim3(16384),  dim3(256), 0, stream, ypt, (float4*)out0);
}